// Round 4
// baseline (1135.742 us; speedup 1.0000x reference)
//
#include <hip/hip_runtime.h>
#include <hip/hip_fp16.h>
#include <math.h>

#define K1 128     // input feature dim
#define C  64      // hidden == output channels
#define SCAN_B 1024
#define NBMAX  256 // max coarse buckets (LDS sizing)
#define BSH    9   // bucket width = 512 nodes
#define WIDTH  512
#define DEPTH  28  // stage depth per bucket (pairs)
#define FLUSH_TILES 8

// ---- edge dtype detection: int64 edges have all-zero high words ----
__global__ void detect_kernel(const int* __restrict__ e, int twoE, int* __restrict__ flag) {
    __shared__ int nz;
    if (threadIdx.x == 0) nz = 0;
    __syncthreads();
    int nchk = twoE / 2; if (nchk > 4096) nchk = 4096;
    int bad = 0;
    for (int i = threadIdx.x; i < nchk; i += blockDim.x)
        if (e[2 * i + 1] != 0) bad = 1;
    if (bad) atomicOr(&nz, 1);
    __syncthreads();
    if (threadIdx.x == 0) *flag = nz ? 0 : 1;   // 1 => int64
}

__device__ __forceinline__ int load_dst(const void* EI, int E, int e, int is64) {
    return is64 ? (int)((const long long*)EI)[(size_t)E + e] : ((const int*)EI)[(size_t)E + e];
}
__device__ __forceinline__ int load_src(const void* EI, int E, int e, int is64) {
    return is64 ? (int)((const long long*)EI)[e] : ((const int*)EI)[e];
}

// ---- pass 1: per-node degree histogram + coarse bucket histogram ----
__global__ __launch_bounds__(256) void hist_kernel(const void* __restrict__ EI, int E,
        const int* __restrict__ flag, int* __restrict__ cnt, int* __restrict__ bcnt,
        int nbuckets) {
    __shared__ int bh[NBMAX];
    for (int i = threadIdx.x; i < NBMAX; i += 256) bh[i] = 0;
    __syncthreads();
    const int is64 = *flag;
    for (int e = blockIdx.x * 256 + threadIdx.x; e < E; e += gridDim.x * 256) {
        int d = load_dst(EI, E, e, is64);
        atomicAdd(&cnt[d], 1);
        int b = d >> BSH;
        if (b < NBMAX) atomicAdd(&bh[b], 1);
    }
    __syncthreads();
    for (int i = threadIdx.x; i < nbuckets; i += 256)
        if (bh[i]) atomicAdd(&bcnt[i], bh[i]);
}

// ---- exclusive scan of cnt -> rowptr (3 phases); dinv fused into phase 1 ----
__global__ __launch_bounds__(SCAN_B) void scan1_kernel(const int* __restrict__ cnt, int n,
        int* __restrict__ ex, int* __restrict__ bsum, float* __restrict__ dinv) {
    __shared__ int s[SCAN_B];
    int i = blockIdx.x * SCAN_B + threadIdx.x;
    int v = (i < n) ? cnt[i] : 0;
    s[threadIdx.x] = v;
    __syncthreads();
    for (int off = 1; off < SCAN_B; off <<= 1) {
        int t = (threadIdx.x >= off) ? s[threadIdx.x - off] : 0;
        __syncthreads();
        s[threadIdx.x] += t;
        __syncthreads();
    }
    if (i < n) {
        ex[i] = s[threadIdx.x] - v;               // exclusive within block
        dinv[i] = rsqrtf((float)(v + 1));         // +1 self-loop
    }
    if (threadIdx.x == SCAN_B - 1) bsum[blockIdx.x] = s[SCAN_B - 1];
}

// wave 0: scan block sums; wave 1: scan bucket counts -> bbase, init tail
__global__ void scan2_kernel(int* __restrict__ bsum, int nb,
        const int* __restrict__ bcnt, int* __restrict__ bbase, int* __restrict__ tail,
        int nbuckets, int Etot) {
    const int lane = threadIdx.x & 63;
    const int wv = threadIdx.x >> 6;
    if (wv == 0) {
        int acc = 0;
        for (int base = 0; base < nb; base += 64) {
            int v = (base + lane < nb) ? bsum[base + lane] : 0;
            int sc = v;
            #pragma unroll
            for (int off = 1; off < 64; off <<= 1) {
                int t = __shfl_up(sc, off, 64);
                if (lane >= off) sc += t;
            }
            if (base + lane < nb) bsum[base + lane] = acc + sc - v;
            acc += __shfl(sc, 63, 64);
        }
    } else if (wv == 1) {
        int acc = 0;
        for (int base = 0; base < nbuckets; base += 64) {
            int v = (base + lane < nbuckets) ? bcnt[base + lane] : 0;
            int sc = v;
            #pragma unroll
            for (int off = 1; off < 64; off <<= 1) {
                int t = __shfl_up(sc, off, 64);
                if (lane >= off) sc += t;
            }
            if (base + lane < nbuckets) {
                int ex = acc + sc - v;
                bbase[base + lane] = ex;
                tail[base + lane] = ex;
            }
            acc += __shfl(sc, 63, 64);
        }
        if (lane == 0) bbase[nbuckets] = Etot;
    }
}

__global__ void scan3_kernel(int* __restrict__ ex, const int* __restrict__ bsum,
                             int n, int Etot) {
    for (int i = blockIdx.x * blockDim.x + threadIdx.x; i < n; i += gridDim.x * blockDim.x)
        ex[i] += bsum[i / SCAN_B];
    if (blockIdx.x == 0 && threadIdx.x == 0) ex[n] = Etot;
}

// ---- pass 2: LDS-staged bucket append of (dst,src) pairs ----
__global__ __launch_bounds__(256) void bucket_kernel(const void* __restrict__ EI, int E,
        const int* __restrict__ flag, uint2* __restrict__ pairs, int* __restrict__ tail,
        int nbuckets) {
    __shared__ uint2 stage[NBMAX][DEPTH];
    __shared__ int scnt[NBMAX];
    for (int i = threadIdx.x; i < NBMAX; i += 256) scnt[i] = 0;
    __syncthreads();
    const int is64 = *flag;
    const int tid = threadIdx.x;
    const int lane = tid & 63;
    const int wv = tid >> 6;
    int chunk = (E + gridDim.x - 1) / gridDim.x;
    int start = blockIdx.x * chunk;
    int end = start + chunk; if (end > E) end = E;

#define FLUSH_STAGE()                                                         \
    do {                                                                      \
        __syncthreads();                                                      \
        for (int b = wv; b < nbuckets; b += 4) {                              \
            int c = scnt[b]; if (c > DEPTH) c = DEPTH;                        \
            if (c > 0) {                                                      \
                int bse = 0;                                                  \
                if (lane == 0) bse = atomicAdd(&tail[b], c);                  \
                bse = __shfl(bse, 0, 64);                                     \
                if (lane < c) pairs[bse + lane] = stage[b][lane];             \
            }                                                                 \
        }                                                                     \
        __syncthreads();                                                      \
        for (int i = tid; i < NBMAX; i += 256) scnt[i] = 0;                   \
        __syncthreads();                                                      \
    } while (0)

    int tilecnt = 0;
    for (int base = start; base < end; base += 256) {
        int e = base + tid;
        if (e < end) {
            int d = load_dst(EI, E, e, is64);
            int s = load_src(EI, E, e, is64);
            int b = d >> BSH;
            int slot = (b < NBMAX) ? atomicAdd(&scnt[b], 1) : DEPTH;
            if (slot < DEPTH) {
                stage[b][slot] = make_uint2((unsigned)d, (unsigned)s);
            } else {
                int pos = atomicAdd(&tail[b], 1);
                pairs[pos] = make_uint2((unsigned)d, (unsigned)s);
            }
        }
        if (++tilecnt == FLUSH_TILES) { tilecnt = 0; FLUSH_STAGE(); }
    }
    FLUSH_STAGE();
#undef FLUSH_STAGE
}

// ---- pass 3: per-bucket local scatter (LDS fill counters, L2-local csr writes) ----
__global__ __launch_bounds__(256) void scatterlocal_kernel(const uint2* __restrict__ pairs,
        const int* __restrict__ bbase, const int* __restrict__ rowptr,
        int* __restrict__ csr, int n) {
    __shared__ int fillL[WIDTH];
    const int b = blockIdx.x;
    const int nb0 = b << BSH;
    int nodes = n - nb0; if (nodes > WIDTH) nodes = WIDTH;
    for (int i = threadIdx.x; i < nodes; i += 256) fillL[i] = rowptr[nb0 + i];
    __syncthreads();
    const int s0 = bbase[b], s1 = bbase[b + 1];
    for (int i = s0 + threadIdx.x; i < s1; i += 256) {
        uint2 p = pairs[i];
        int pos = atomicAdd(&fillL[(int)p.x - nb0], 1);
        csr[pos] = (int)p.y;
    }
}

// ---- G = (X @ W) * dinv[row] stored f16; one wave per R rows, lane = out col ----
template<int K, int R>
__global__ __launch_bounds__(256) void gemm_kernel(const float* __restrict__ X,
        const float* __restrict__ W, const float* __restrict__ dinv,
        __half* __restrict__ G, int n)
{
    __shared__ float Ws[K * C];
    for (int i = threadIdx.x; i < K * C; i += 256) Ws[i] = W[i];
    __syncthreads();
    const int lane = threadIdx.x & 63;
    const int wave = __builtin_amdgcn_readfirstlane((int)(threadIdx.x >> 6));
    const int waves = gridDim.x * 4;
    for (int base = (blockIdx.x * 4 + wave) * R; base < n; base += waves * R) {
        float acc[R];
        #pragma unroll
        for (int r = 0; r < R; ++r) acc[r] = 0.0f;
        if (base + R <= n) {
            for (int k = 0; k < K; ++k) {
                float w = Ws[k * C + lane];
                #pragma unroll
                for (int r = 0; r < R; ++r)
                    acc[r] = fmaf(X[(size_t)(base + r) * K + k], w, acc[r]);
            }
            #pragma unroll
            for (int r = 0; r < R; ++r)
                G[(size_t)(base + r) * C + lane] = __float2half_rn(acc[r] * dinv[base + r]);
        } else {
            for (int r = 0; r < R; ++r) {
                if (base + r >= n) break;
                float a = 0.0f;
                for (int k = 0; k < K; ++k)
                    a = fmaf(X[(size_t)(base + r) * K + k], Ws[k * C + lane], a);
                G[(size_t)(base + r) * C + lane] = __float2half_rn(a * dinv[base + r]);
            }
        }
    }
}

// ---- CSR gather (f16 G, f32 accum): one wave per dst row ----
// MODE 0 = relu+bias -> f32 Out ; MODE 1 = bias+logsoftmax -> f32 Out
template<int MODE>
__global__ __launch_bounds__(256) void gather_kernel(const int* __restrict__ rowptr,
        const int* __restrict__ csr, const __half* __restrict__ G,
        const float* __restrict__ dinv, const float* __restrict__ bias,
        float* __restrict__ Out, int n)
{
    const int lane = threadIdx.x & 63;
    const int v = __builtin_amdgcn_readfirstlane((int)(blockIdx.x * 4 + (threadIdx.x >> 6)));
    if (v >= n) return;
    const int start = __builtin_amdgcn_readfirstlane(rowptr[v]);
    const int end   = __builtin_amdgcn_readfirstlane(rowptr[v + 1]);
    float a0 = __half2float(G[(size_t)v * C + lane]);   // self-loop term
    float a1 = 0.f, a2 = 0.f, a3 = 0.f;
    for (int base = start; base < end; base += 64) {
        int m = end - base; if (m > 64) m = 64;
        int idx = (lane < m) ? csr[base + lane] : 0;
        int j = 0;
        for (; j + 4 <= m; j += 4) {
            int s0 = __shfl(idx, j,     64);
            int s1 = __shfl(idx, j + 1, 64);
            int s2 = __shfl(idx, j + 2, 64);
            int s3 = __shfl(idx, j + 3, 64);
            a0 += __half2float(G[(size_t)s0 * C + lane]);
            a1 += __half2float(G[(size_t)s1 * C + lane]);
            a2 += __half2float(G[(size_t)s2 * C + lane]);
            a3 += __half2float(G[(size_t)s3 * C + lane]);
        }
        for (; j < m; ++j) {
            int s = __shfl(idx, j, 64);
            a0 += __half2float(G[(size_t)s * C + lane]);
        }
    }
    float acc = (a0 + a1) + (a2 + a3);
    float y = fmaf(acc, dinv[v], bias[lane]);
    if (MODE == 0) {
        Out[(size_t)v * C + lane] = y > 0.f ? y : 0.f;
    } else {
        float mx = y;
        #pragma unroll
        for (int off = 32; off > 0; off >>= 1) mx = fmaxf(mx, __shfl_xor(mx, off, 64));
        float ex = expf(y - mx);
        float l = ex;
        #pragma unroll
        for (int off = 32; off > 0; off >>= 1) l += __shfl_xor(l, off, 64);
        Out[(size_t)v * C + lane] = y - mx - logf(l);
    }
}

static inline size_t align16(size_t x) { return (x + 15) & ~(size_t)15; }

extern "C" void kernel_launch(void* const* d_in, const int* in_sizes, int n_in,
                              void* d_out, int out_size, void* d_ws, size_t ws_size,
                              hipStream_t stream)
{
    const float* X  = (const float*)d_in[0];
    const void*  EI = d_in[1];
    const float* W1 = (const float*)d_in[3];
    const float* b1 = (const float*)d_in[4];
    const float* W2 = (const float*)d_in[5];
    const float* b2 = (const float*)d_in[6];
    float* Out = (float*)d_out;

    const int n    = in_sizes[0] / K1;
    const int E    = in_sizes[1] / 2;
    const int twoE = 2 * E;
    const int nb   = (n + SCAN_B - 1) / SCAN_B;
    const int nbuckets = (n + WIDTH - 1) >> BSH;

    // workspace layout (~33 MB)
    char* ws = (char*)d_ws;
    size_t off = 0;
    uint2* pairs  = (uint2*)(ws + off); off = align16(off + (size_t)E * 8);
    int*   csr    = (int*)(ws + off);   off = align16(off + (size_t)E * 4);
    int*   rowptr = (int*)(ws + off);   off = align16(off + (size_t)(n + 1) * 4);
    int*   cnt    = (int*)(ws + off);   off += (size_t)n * 4;          // cnt|bcnt contiguous
    int*   bcnt   = (int*)(ws + off);   off = align16(off + (size_t)NBMAX * 4);
    int*   bsum   = (int*)(ws + off);   off = align16(off + (size_t)(nb + 1) * 4);
    int*   bbase  = (int*)(ws + off);   off = align16(off + (size_t)(NBMAX + 1) * 4);
    int*   tail   = (int*)(ws + off);   off = align16(off + (size_t)NBMAX * 4);
    int*   flag   = (int*)(ws + off);   off = align16(off + 16);
    float* dinv   = (float*)(ws + off); off = align16(off + (size_t)n * 4);
    __half* G     = (__half*)(ws + off); off = align16(off + (size_t)n * C * 2);
    float* H      = Out;               // layer-1 activations staged in d_out

    hipLaunchKernelGGL(detect_kernel, dim3(1), dim3(256), 0, stream, (const int*)EI, twoE, flag);
    hipMemsetAsync(cnt, 0, ((size_t)n + NBMAX) * 4, stream);

    // CSR build
    hipLaunchKernelGGL(hist_kernel,  dim3(1024), dim3(256), 0, stream, EI, E, flag, cnt, bcnt, nbuckets);
    hipLaunchKernelGGL(scan1_kernel, dim3(nb), dim3(SCAN_B), 0, stream, cnt, n, rowptr, bsum, dinv);
    hipLaunchKernelGGL(scan2_kernel, dim3(1), dim3(128), 0, stream, bsum, nb, bcnt, bbase, tail, nbuckets, E);
    hipLaunchKernelGGL(scan3_kernel, dim3(1024), dim3(256), 0, stream, rowptr, bsum, n, E);
    hipLaunchKernelGGL(bucket_kernel, dim3(512), dim3(256), 0, stream, EI, E, flag, pairs, tail, nbuckets);
    hipLaunchKernelGGL(scatterlocal_kernel, dim3(nbuckets), dim3(256), 0, stream, pairs, bbase, rowptr, csr, n);

    const int ngb = (n + 3) / 4;   // one wave per row

    // layer 1: G = f16((X@W1)*dinv) ; H = relu(gather(G)*dinv + b1)
    hipLaunchKernelGGL((gemm_kernel<K1, 8>), dim3(2048), dim3(256), 0, stream, X, W1, dinv, G, n);
    hipLaunchKernelGGL((gather_kernel<0>), dim3(ngb), dim3(256), 0, stream, rowptr, csr, G, dinv, b1, H, n);

    // layer 2: G = f16((H@W2)*dinv) ; Out = log_softmax(gather(G)*dinv + b2)
    hipLaunchKernelGGL((gemm_kernel<C, 8>), dim3(2048), dim3(256), 0, stream, H, W2, dinv, G, n);
    hipLaunchKernelGGL((gather_kernel<1>), dim3(ngb), dim3(256), 0, stream, rowptr, csr, G, dinv, b2, Out, n);
}

// Round 5
// 524.729 us; speedup vs baseline: 2.1644x; 2.1644x over previous
//
#include <hip/hip_runtime.h>
#include <hip/hip_fp16.h>
#include <math.h>

#define K1 128     // input feature dim
#define C  64      // hidden == output channels
#define SCAN_B 1024

// ---- edge dtype detection: int64 edges have all-zero high words ----
__global__ void detect_kernel(const int* __restrict__ e, int twoE, int* __restrict__ flag) {
    __shared__ int nz;
    if (threadIdx.x == 0) nz = 0;
    __syncthreads();
    int nchk = twoE / 2; if (nchk > 4096) nchk = 4096;
    int bad = 0;
    for (int i = threadIdx.x; i < nchk; i += blockDim.x)
        if (e[2 * i + 1] != 0) bad = 1;
    if (bad) atomicOr(&nz, 1);
    __syncthreads();
    if (threadIdx.x == 0) *flag = nz ? 0 : 1;   // 1 => int64
}

__device__ __forceinline__ int load_dst(const void* EI, int E, int e, int is64) {
    return is64 ? (int)((const long long*)EI)[(size_t)E + e] : ((const int*)EI)[(size_t)E + e];
}
__device__ __forceinline__ int load_src(const void* EI, int E, int e, int is64) {
    return is64 ? (int)((const long long*)EI)[e] : ((const int*)EI)[e];
}

// ---- per-node in-degree histogram (reads EI directly) ----
__global__ __launch_bounds__(256) void hist_kernel(const void* __restrict__ EI, int E,
        const int* __restrict__ flag, int* __restrict__ cnt) {
    const int is64 = *flag;
    for (int e = blockIdx.x * 256 + threadIdx.x; e < E; e += gridDim.x * 256)
        atomicAdd(&cnt[load_dst(EI, E, e, is64)], 1);
}

// ---- exclusive scan of cnt -> rowptr (3 phases); dinv fused into phase 1 ----
__global__ __launch_bounds__(SCAN_B) void scan1_kernel(const int* __restrict__ cnt, int n,
        int* __restrict__ ex, int* __restrict__ bsum, float* __restrict__ dinv) {
    __shared__ int s[SCAN_B];
    int i = blockIdx.x * SCAN_B + threadIdx.x;
    int v = (i < n) ? cnt[i] : 0;
    s[threadIdx.x] = v;
    __syncthreads();
    for (int off = 1; off < SCAN_B; off <<= 1) {
        int t = (threadIdx.x >= off) ? s[threadIdx.x - off] : 0;
        __syncthreads();
        s[threadIdx.x] += t;
        __syncthreads();
    }
    if (i < n) {
        ex[i] = s[threadIdx.x] - v;               // exclusive within block
        dinv[i] = rsqrtf((float)(v + 1));         // +1 self-loop
    }
    if (threadIdx.x == SCAN_B - 1) bsum[blockIdx.x] = s[SCAN_B - 1];
}

__global__ void scan2_kernel(int* __restrict__ bsum, int nb) {
    const int lane = threadIdx.x & 63;
    int acc = 0;
    for (int base = 0; base < nb; base += 64) {
        int v = (base + lane < nb) ? bsum[base + lane] : 0;
        int sc = v;
        #pragma unroll
        for (int off = 1; off < 64; off <<= 1) {
            int t = __shfl_up(sc, off, 64);
            if (lane >= off) sc += t;
        }
        if (base + lane < nb) bsum[base + lane] = acc + sc - v;   // exclusive
        acc += __shfl(sc, 63, 64);
    }
}

__global__ void scan3_kernel(int* __restrict__ ex, const int* __restrict__ bsum,
                             int* __restrict__ fill, int n, int Etot) {
    for (int i = blockIdx.x * blockDim.x + threadIdx.x; i < n; i += gridDim.x * blockDim.x) {
        int v = ex[i] + bsum[i / SCAN_B];
        ex[i] = v;
        fill[i] = v;
    }
    if (blockIdx.x == 0 && threadIdx.x == 0) ex[n] = Etot;
}

// ---- scatter edges into CSR order (position via atomic on fill) ----
__global__ __launch_bounds__(256) void scatter_kernel(const void* __restrict__ EI, int E,
        const int* __restrict__ flag, int* __restrict__ fill, int* __restrict__ csr) {
    const int is64 = *flag;
    for (int e = blockIdx.x * 256 + threadIdx.x; e < E; e += gridDim.x * 256) {
        int d = load_dst(EI, E, e, is64);
        int s = load_src(EI, E, e, is64);
        int pos = atomicAdd(&fill[d], 1);
        csr[pos] = s;
    }
}

// ---- G = (X @ W) * dinv[row] stored f16; one wave per R rows, lane = out col ----
template<int K, int R>
__global__ __launch_bounds__(256) void gemm_kernel(const float* __restrict__ X,
        const float* __restrict__ W, const float* __restrict__ dinv,
        __half* __restrict__ G, int n)
{
    __shared__ float Ws[K * C];
    for (int i = threadIdx.x; i < K * C; i += 256) Ws[i] = W[i];
    __syncthreads();
    const int lane = threadIdx.x & 63;
    const int wave = __builtin_amdgcn_readfirstlane((int)(threadIdx.x >> 6));
    const int waves = gridDim.x * 4;
    for (int base = (blockIdx.x * 4 + wave) * R; base < n; base += waves * R) {
        float acc[R];
        #pragma unroll
        for (int r = 0; r < R; ++r) acc[r] = 0.0f;
        if (base + R <= n) {
            for (int k = 0; k < K; ++k) {
                float w = Ws[k * C + lane];
                #pragma unroll
                for (int r = 0; r < R; ++r)
                    acc[r] = fmaf(X[(size_t)(base + r) * K + k], w, acc[r]);
            }
            #pragma unroll
            for (int r = 0; r < R; ++r)
                G[(size_t)(base + r) * C + lane] = __float2half_rn(acc[r] * dinv[base + r]);
        } else {
            for (int r = 0; r < R; ++r) {
                if (base + r >= n) break;
                float a = 0.0f;
                for (int k = 0; k < K; ++k)
                    a = fmaf(X[(size_t)(base + r) * K + k], Ws[k * C + lane], a);
                G[(size_t)(base + r) * C + lane] = __float2half_rn(a * dinv[base + r]);
            }
        }
    }
}

// ---- fused: H = relu(gather(G)*dinv + b1); G2 = f16((H @ W2) * dinv) ----
// One wave per row (grid-stride). Each lane keeps its W2 column in 64 regs;
// the H row is staged in wave-local LDS and read back as float4 broadcasts
// (DS ops from one wave execute in order -> no barrier needed).
__global__ __launch_bounds__(256) void gather_fused_kernel(const int* __restrict__ rowptr,
        const int* __restrict__ csr, const __half* __restrict__ G,
        const float* __restrict__ dinv, const float* __restrict__ b1,
        const float* __restrict__ W2, __half* __restrict__ G2, int n)
{
    __shared__ __align__(16) float Hrow[4][C];
    const int lane = threadIdx.x & 63;
    const int wv = __builtin_amdgcn_readfirstlane((int)(threadIdx.x >> 6));
    float w[C];
    #pragma unroll
    for (int k = 0; k < C; ++k) w[k] = W2[k * C + lane];   // column, coalesced
    const float bias = b1[lane];
    const int nwaves = gridDim.x * 4;
    for (int v = __builtin_amdgcn_readfirstlane(blockIdx.x * 4 + wv); v < n; v += nwaves) {
        const int start = __builtin_amdgcn_readfirstlane(rowptr[v]);
        const int end   = __builtin_amdgcn_readfirstlane(rowptr[v + 1]);
        float a0 = __half2float(G[(size_t)v * C + lane]);   // self-loop
        float a1 = 0.f, a2 = 0.f, a3 = 0.f;
        for (int base = start; base < end; base += 64) {
            int m = end - base; if (m > 64) m = 64;
            int idx = (lane < m) ? csr[base + lane] : 0;
            int j = 0;
            for (; j + 4 <= m; j += 4) {
                int s0 = __shfl(idx, j,     64);
                int s1 = __shfl(idx, j + 1, 64);
                int s2 = __shfl(idx, j + 2, 64);
                int s3 = __shfl(idx, j + 3, 64);
                a0 += __half2float(G[(size_t)s0 * C + lane]);
                a1 += __half2float(G[(size_t)s1 * C + lane]);
                a2 += __half2float(G[(size_t)s2 * C + lane]);
                a3 += __half2float(G[(size_t)s3 * C + lane]);
            }
            for (; j < m; ++j) {
                int s = __shfl(idx, j, 64);
                a0 += __half2float(G[(size_t)s * C + lane]);
            }
        }
        float y = fmaf((a0 + a1) + (a2 + a3), dinv[v], bias);
        y = y > 0.f ? y : 0.f;                   // ReLU
        Hrow[wv][lane] = y;                      // wave-local stage (in-order DS)
        float o = 0.f;
        #pragma unroll
        for (int k0 = 0; k0 < C / 4; ++k0) {
            float4 h4 = *(const float4*)&Hrow[wv][k0 * 4];   // broadcast read
            o = fmaf(h4.x, w[4 * k0 + 0], o);
            o = fmaf(h4.y, w[4 * k0 + 1], o);
            o = fmaf(h4.z, w[4 * k0 + 2], o);
            o = fmaf(h4.w, w[4 * k0 + 3], o);
        }
        G2[(size_t)v * C + lane] = __float2half_rn(o * dinv[v]);
    }
}

// ---- final CSR gather (f16 G2): bias + log_softmax -> f32 Out ----
__global__ __launch_bounds__(256) void gather_ls_kernel(const int* __restrict__ rowptr,
        const int* __restrict__ csr, const __half* __restrict__ G,
        const float* __restrict__ dinv, const float* __restrict__ bias,
        float* __restrict__ Out, int n)
{
    const int lane = threadIdx.x & 63;
    const int v = __builtin_amdgcn_readfirstlane((int)(blockIdx.x * 4 + (threadIdx.x >> 6)));
    if (v >= n) return;
    const int start = __builtin_amdgcn_readfirstlane(rowptr[v]);
    const int end   = __builtin_amdgcn_readfirstlane(rowptr[v + 1]);
    float a0 = __half2float(G[(size_t)v * C + lane]);   // self-loop
    float a1 = 0.f, a2 = 0.f, a3 = 0.f;
    for (int base = start; base < end; base += 64) {
        int m = end - base; if (m > 64) m = 64;
        int idx = (lane < m) ? csr[base + lane] : 0;
        int j = 0;
        for (; j + 4 <= m; j += 4) {
            int s0 = __shfl(idx, j,     64);
            int s1 = __shfl(idx, j + 1, 64);
            int s2 = __shfl(idx, j + 2, 64);
            int s3 = __shfl(idx, j + 3, 64);
            a0 += __half2float(G[(size_t)s0 * C + lane]);
            a1 += __half2float(G[(size_t)s1 * C + lane]);
            a2 += __half2float(G[(size_t)s2 * C + lane]);
            a3 += __half2float(G[(size_t)s3 * C + lane]);
        }
        for (; j < m; ++j) {
            int s = __shfl(idx, j, 64);
            a0 += __half2float(G[(size_t)s * C + lane]);
        }
    }
    float y = fmaf((a0 + a1) + (a2 + a3), dinv[v], bias[lane]);
    float mx = y;
    #pragma unroll
    for (int off = 32; off > 0; off >>= 1) mx = fmaxf(mx, __shfl_xor(mx, off, 64));
    float ex = expf(y - mx);
    float l = ex;
    #pragma unroll
    for (int off = 32; off > 0; off >>= 1) l += __shfl_xor(l, off, 64);
    Out[(size_t)v * C + lane] = y - mx - logf(l);
}

static inline size_t align16(size_t x) { return (x + 15) & ~(size_t)15; }

extern "C" void kernel_launch(void* const* d_in, const int* in_sizes, int n_in,
                              void* d_out, int out_size, void* d_ws, size_t ws_size,
                              hipStream_t stream)
{
    const float* X  = (const float*)d_in[0];
    const void*  EI = d_in[1];
    const float* W1 = (const float*)d_in[3];
    const float* b1 = (const float*)d_in[4];
    const float* W2 = (const float*)d_in[5];
    const float* b2 = (const float*)d_in[6];
    float* Out = (float*)d_out;

    const int n    = in_sizes[0] / K1;
    const int E    = in_sizes[1] / 2;
    const int twoE = 2 * E;
    const int nb   = (n + SCAN_B - 1) / SCAN_B;

    // workspace layout (~34 MB)
    char* ws = (char*)d_ws;
    size_t off = 0;
    int*    csr    = (int*)(ws + off);    off = align16(off + (size_t)E * 4);
    int*    rowptr = (int*)(ws + off);    off = align16(off + (size_t)(n + 1) * 4);
    int*    cnt    = (int*)(ws + off);    off = align16(off + (size_t)n * 4);
    int*    bsum   = (int*)(ws + off);    off = align16(off + (size_t)(nb + 1) * 4);
    int*    flag   = (int*)(ws + off);    off = align16(off + 16);
    float*  dinv   = (float*)(ws + off);  off = align16(off + (size_t)n * 4);
    __half* G      = (__half*)(ws + off); off = align16(off + (size_t)n * C * 2);
    __half* G2     = (__half*)(ws + off); off = align16(off + (size_t)n * C * 2);
    int*    fill   = cnt;                 // cnt dead after scan1

    hipLaunchKernelGGL(detect_kernel, dim3(1), dim3(256), 0, stream, (const int*)EI, twoE, flag);
    hipMemsetAsync(cnt, 0, (size_t)n * 4, stream);

    // CSR build
    hipLaunchKernelGGL(hist_kernel,  dim3(1024), dim3(256), 0, stream, EI, E, flag, cnt);
    hipLaunchKernelGGL(scan1_kernel, dim3(nb), dim3(SCAN_B), 0, stream, cnt, n, rowptr, bsum, dinv);
    hipLaunchKernelGGL(scan2_kernel, dim3(1), dim3(64), 0, stream, bsum, nb);
    hipLaunchKernelGGL(scan3_kernel, dim3(1024), dim3(256), 0, stream, rowptr, bsum, fill, n, E);
    hipLaunchKernelGGL(scatter_kernel, dim3(2048), dim3(256), 0, stream, EI, E, flag, fill, csr);

    // layer 1 transform: G = f16((X@W1)*dinv)
    hipLaunchKernelGGL((gemm_kernel<K1, 8>), dim3(2048), dim3(256), 0, stream, X, W1, dinv, G, n);
    // fused: gather(G) -> relu -> @W2 -> G2
    hipLaunchKernelGGL(gather_fused_kernel, dim3(2048), dim3(256), 0, stream,
                       rowptr, csr, G, dinv, b1, W2, G2, n);
    // final gather + bias + log_softmax
    const int ngb = (n + 3) / 4;
    hipLaunchKernelGGL(gather_ls_kernel, dim3(ngb), dim3(256), 0, stream,
                       rowptr, csr, G2, dinv, b2, Out, n);
}

// Round 6
// 484.160 us; speedup vs baseline: 2.3458x; 1.0838x over previous
//
#include <hip/hip_runtime.h>
#include <hip/hip_fp16.h>
#include <math.h>

#define K1 128     // input feature dim
#define C  64      // hidden == output channels
#define SCAN_B 1024
#define NPART 8    // dst-range partitions == XCD count (bid%8 round-robin)

// ---- edge dtype detection: int64 edges have all-zero high words ----
__global__ void detect_kernel(const int* __restrict__ e, int twoE, int* __restrict__ flag) {
    __shared__ int nz;
    if (threadIdx.x == 0) nz = 0;
    __syncthreads();
    int nchk = twoE / 2; if (nchk > 4096) nchk = 4096;
    int bad = 0;
    for (int i = threadIdx.x; i < nchk; i += blockDim.x)
        if (e[2 * i + 1] != 0) bad = 1;
    if (bad) atomicOr(&nz, 1);
    __syncthreads();
    if (threadIdx.x == 0) *flag = nz ? 0 : 1;   // 1 => int64
}

__device__ __forceinline__ int load_dst(const void* EI, int E, int e, int is64) {
    return is64 ? (int)((const long long*)EI)[(size_t)E + e] : ((const int*)EI)[(size_t)E + e];
}
__device__ __forceinline__ int load_src(const void* EI, int E, int e, int is64) {
    return is64 ? (int)((const long long*)EI)[e] : ((const int*)EI)[e];
}

// ---- per-node in-degree histogram, dst-range partitioned per XCD ----
// block b handles partition b&7; scans all edges, commits only in-range ones.
// cnt lines then have single-XCD writers -> L2-local atomics, no ping-pong.
__global__ __launch_bounds__(256) void hist_kernel(const void* __restrict__ EI, int E,
        const int* __restrict__ flag, int* __restrict__ cnt, int n) {
    const int is64 = *flag;
    const int part = blockIdx.x & (NPART - 1);
    const int span = (n + NPART - 1) / NPART;
    const int lo = part * span;
    const int hi = (lo + span < n) ? lo + span : n;
    const int blk = blockIdx.x >> 3, nblk = gridDim.x >> 3;
    for (int e = blk * 256 + threadIdx.x; e < E; e += nblk * 256) {
        int d = load_dst(EI, E, e, is64);
        if (d >= lo && d < hi) atomicAdd(&cnt[d], 1);
    }
}

// ---- exclusive scan of cnt -> rowptr (3 phases); dinv fused into phase 1 ----
__global__ __launch_bounds__(SCAN_B) void scan1_kernel(const int* __restrict__ cnt, int n,
        int* __restrict__ ex, int* __restrict__ bsum, float* __restrict__ dinv) {
    __shared__ int s[SCAN_B];
    int i = blockIdx.x * SCAN_B + threadIdx.x;
    int v = (i < n) ? cnt[i] : 0;
    s[threadIdx.x] = v;
    __syncthreads();
    for (int off = 1; off < SCAN_B; off <<= 1) {
        int t = (threadIdx.x >= off) ? s[threadIdx.x - off] : 0;
        __syncthreads();
        s[threadIdx.x] += t;
        __syncthreads();
    }
    if (i < n) {
        ex[i] = s[threadIdx.x] - v;               // exclusive within block
        dinv[i] = rsqrtf((float)(v + 1));         // +1 self-loop
    }
    if (threadIdx.x == SCAN_B - 1) bsum[blockIdx.x] = s[SCAN_B - 1];
}

__global__ void scan2_kernel(int* __restrict__ bsum, int nb) {
    const int lane = threadIdx.x & 63;
    int acc = 0;
    for (int base = 0; base < nb; base += 64) {
        int v = (base + lane < nb) ? bsum[base + lane] : 0;
        int sc = v;
        #pragma unroll
        for (int off = 1; off < 64; off <<= 1) {
            int t = __shfl_up(sc, off, 64);
            if (lane >= off) sc += t;
        }
        if (base + lane < nb) bsum[base + lane] = acc + sc - v;   // exclusive
        acc += __shfl(sc, 63, 64);
    }
}

__global__ void scan3_kernel(int* __restrict__ ex, const int* __restrict__ bsum,
                             int* __restrict__ fill, int n, int Etot) {
    for (int i = blockIdx.x * blockDim.x + threadIdx.x; i < n; i += gridDim.x * blockDim.x) {
        int v = ex[i] + bsum[i / SCAN_B];
        ex[i] = v;
        fill[i] = v;
    }
    if (blockIdx.x == 0 && threadIdx.x == 0) ex[n] = Etot;
}

// ---- scatter into CSR order, dst-range partitioned per XCD ----
// All writers of a csr/fill line are on one XCD -> lines fill in that L2
// before writeback (kills the 16x write amplification seen in R5).
__global__ __launch_bounds__(256) void scatter_kernel(const void* __restrict__ EI, int E,
        const int* __restrict__ flag, int* __restrict__ fill, int* __restrict__ csr,
        int n) {
    const int is64 = *flag;
    const int part = blockIdx.x & (NPART - 1);
    const int span = (n + NPART - 1) / NPART;
    const int lo = part * span;
    const int hi = (lo + span < n) ? lo + span : n;
    const int blk = blockIdx.x >> 3, nblk = gridDim.x >> 3;
    for (int e = blk * 256 + threadIdx.x; e < E; e += nblk * 256) {
        int d = load_dst(EI, E, e, is64);
        if (d >= lo && d < hi) {
            int s = load_src(EI, E, e, is64);
            int pos = atomicAdd(&fill[d], 1);
            csr[pos] = s;
        }
    }
}

// ---- G = (X @ W) * dinv[row] stored f16; one wave per R rows, lane = out col ----
template<int K, int R>
__global__ __launch_bounds__(256) void gemm_kernel(const float* __restrict__ X,
        const float* __restrict__ W, const float* __restrict__ dinv,
        __half* __restrict__ G, int n)
{
    __shared__ float Ws[K * C];
    for (int i = threadIdx.x; i < K * C; i += 256) Ws[i] = W[i];
    __syncthreads();
    const int lane = threadIdx.x & 63;
    const int wave = __builtin_amdgcn_readfirstlane((int)(threadIdx.x >> 6));
    const int waves = gridDim.x * 4;
    for (int base = (blockIdx.x * 4 + wave) * R; base < n; base += waves * R) {
        float acc[R];
        #pragma unroll
        for (int r = 0; r < R; ++r) acc[r] = 0.0f;
        if (base + R <= n) {
            for (int k = 0; k < K; ++k) {
                float w = Ws[k * C + lane];
                #pragma unroll
                for (int r = 0; r < R; ++r)
                    acc[r] = fmaf(X[(size_t)(base + r) * K + k], w, acc[r]);
            }
            #pragma unroll
            for (int r = 0; r < R; ++r)
                G[(size_t)(base + r) * C + lane] = __float2half_rn(acc[r] * dinv[base + r]);
        } else {
            for (int r = 0; r < R; ++r) {
                if (base + r >= n) break;
                float a = 0.0f;
                for (int k = 0; k < K; ++k)
                    a = fmaf(X[(size_t)(base + r) * K + k], Ws[k * C + lane], a);
                G[(size_t)(base + r) * C + lane] = __float2half_rn(a * dinv[base + r]);
            }
        }
    }
}

// 8-deep gather accumulation (latency-bound random loads; VGPRs are free here)
#define GATHER_ROW(G_, start_, end_)                                          \
    float a0 = __half2float(G_[(size_t)v * C + lane]);                        \
    float a1 = 0.f, a2 = 0.f, a3 = 0.f, a4 = 0.f, a5 = 0.f, a6 = 0.f, a7 = 0.f; \
    for (int base = start_; base < end_; base += 64) {                        \
        int m = end_ - base; if (m > 64) m = 64;                              \
        int idx = (lane < m) ? csr[base + lane] : 0;                          \
        int j = 0;                                                            \
        for (; j + 8 <= m; j += 8) {                                          \
            int s0 = __shfl(idx, j,     64);                                  \
            int s1 = __shfl(idx, j + 1, 64);                                  \
            int s2 = __shfl(idx, j + 2, 64);                                  \
            int s3 = __shfl(idx, j + 3, 64);                                  \
            int s4 = __shfl(idx, j + 4, 64);                                  \
            int s5 = __shfl(idx, j + 5, 64);                                  \
            int s6 = __shfl(idx, j + 6, 64);                                  \
            int s7 = __shfl(idx, j + 7, 64);                                  \
            a0 += __half2float(G_[(size_t)s0 * C + lane]);                    \
            a1 += __half2float(G_[(size_t)s1 * C + lane]);                    \
            a2 += __half2float(G_[(size_t)s2 * C + lane]);                    \
            a3 += __half2float(G_[(size_t)s3 * C + lane]);                    \
            a4 += __half2float(G_[(size_t)s4 * C + lane]);                    \
            a5 += __half2float(G_[(size_t)s5 * C + lane]);                    \
            a6 += __half2float(G_[(size_t)s6 * C + lane]);                    \
            a7 += __half2float(G_[(size_t)s7 * C + lane]);                    \
        }                                                                     \
        for (; j < m; ++j) {                                                  \
            int s = __shfl(idx, j, 64);                                       \
            a0 += __half2float(G_[(size_t)s * C + lane]);                     \
        }                                                                     \
    }                                                                         \
    float acc = ((a0 + a1) + (a2 + a3)) + ((a4 + a5) + (a6 + a7));

// ---- fused: H = relu(gather(G)*dinv + b1); G2 = f16((H @ W2) * dinv) ----
__global__ __launch_bounds__(256) void gather_fused_kernel(const int* __restrict__ rowptr,
        const int* __restrict__ csr, const __half* __restrict__ G,
        const float* __restrict__ dinv, const float* __restrict__ b1,
        const float* __restrict__ W2, __half* __restrict__ G2, int n)
{
    __shared__ __align__(16) float Hrow[4][C];
    const int lane = threadIdx.x & 63;
    const int wv = __builtin_amdgcn_readfirstlane((int)(threadIdx.x >> 6));
    float w[C];
    #pragma unroll
    for (int k = 0; k < C; ++k) w[k] = W2[k * C + lane];   // column, coalesced
    const float bias = b1[lane];
    const int nwaves = gridDim.x * 4;
    for (int v = __builtin_amdgcn_readfirstlane(blockIdx.x * 4 + wv); v < n; v += nwaves) {
        const int start = __builtin_amdgcn_readfirstlane(rowptr[v]);
        const int end   = __builtin_amdgcn_readfirstlane(rowptr[v + 1]);
        GATHER_ROW(G, start, end)
        float y = fmaf(acc, dinv[v], bias);
        y = y > 0.f ? y : 0.f;                   // ReLU
        Hrow[wv][lane] = y;                      // wave-local stage (in-order DS)
        float o = 0.f;
        #pragma unroll
        for (int k0 = 0; k0 < C / 4; ++k0) {
            float4 h4 = *(const float4*)&Hrow[wv][k0 * 4];   // broadcast read
            o = fmaf(h4.x, w[4 * k0 + 0], o);
            o = fmaf(h4.y, w[4 * k0 + 1], o);
            o = fmaf(h4.z, w[4 * k0 + 2], o);
            o = fmaf(h4.w, w[4 * k0 + 3], o);
        }
        G2[(size_t)v * C + lane] = __float2half_rn(o * dinv[v]);
    }
}

// ---- final CSR gather (f16 G2): bias + log_softmax -> f32 Out ----
__global__ __launch_bounds__(256) void gather_ls_kernel(const int* __restrict__ rowptr,
        const int* __restrict__ csr, const __half* __restrict__ G2,
        const float* __restrict__ dinv, const float* __restrict__ bias,
        float* __restrict__ Out, int n)
{
    const int lane = threadIdx.x & 63;
    const int v = __builtin_amdgcn_readfirstlane((int)(blockIdx.x * 4 + (threadIdx.x >> 6)));
    if (v >= n) return;
    const int start = __builtin_amdgcn_readfirstlane(rowptr[v]);
    const int end   = __builtin_amdgcn_readfirstlane(rowptr[v + 1]);
    GATHER_ROW(G2, start, end)
    float y = fmaf(acc, dinv[v], bias[lane]);
    float mx = y;
    #pragma unroll
    for (int off = 32; off > 0; off >>= 1) mx = fmaxf(mx, __shfl_xor(mx, off, 64));
    float ex = expf(y - mx);
    float l = ex;
    #pragma unroll
    for (int off = 32; off > 0; off >>= 1) l += __shfl_xor(l, off, 64);
    Out[(size_t)v * C + lane] = y - mx - logf(l);
}

static inline size_t align16(size_t x) { return (x + 15) & ~(size_t)15; }

extern "C" void kernel_launch(void* const* d_in, const int* in_sizes, int n_in,
                              void* d_out, int out_size, void* d_ws, size_t ws_size,
                              hipStream_t stream)
{
    const float* X  = (const float*)d_in[0];
    const void*  EI = d_in[1];
    const float* W1 = (const float*)d_in[3];
    const float* b1 = (const float*)d_in[4];
    const float* W2 = (const float*)d_in[5];
    const float* b2 = (const float*)d_in[6];
    float* Out = (float*)d_out;

    const int n    = in_sizes[0] / K1;
    const int E    = in_sizes[1] / 2;
    const int twoE = 2 * E;
    const int nb   = (n + SCAN_B - 1) / SCAN_B;

    // workspace layout (~34 MB)
    char* ws = (char*)d_ws;
    size_t off = 0;
    int*    csr    = (int*)(ws + off);    off = align16(off + (size_t)E * 4);
    int*    rowptr = (int*)(ws + off);    off = align16(off + (size_t)(n + 1) * 4);
    int*    cnt    = (int*)(ws + off);    off = align16(off + (size_t)n * 4);
    int*    bsum   = (int*)(ws + off);    off = align16(off + (size_t)(nb + 1) * 4);
    int*    flag   = (int*)(ws + off);    off = align16(off + 16);
    float*  dinv   = (float*)(ws + off);  off = align16(off + (size_t)n * 4);
    __half* G      = (__half*)(ws + off); off = align16(off + (size_t)n * C * 2);
    __half* G2     = (__half*)(ws + off); off = align16(off + (size_t)n * C * 2);
    int*    fill   = cnt;                 // cnt dead after scan1

    hipLaunchKernelGGL(detect_kernel, dim3(1), dim3(256), 0, stream, (const int*)EI, twoE, flag);
    hipMemsetAsync(cnt, 0, (size_t)n * 4, stream);

    // CSR build (hist & scatter dst-partitioned, XCD-local via bid%8)
    hipLaunchKernelGGL(hist_kernel,  dim3(2048), dim3(256), 0, stream, EI, E, flag, cnt, n);
    hipLaunchKernelGGL(scan1_kernel, dim3(nb), dim3(SCAN_B), 0, stream, cnt, n, rowptr, bsum, dinv);
    hipLaunchKernelGGL(scan2_kernel, dim3(1), dim3(64), 0, stream, bsum, nb);
    hipLaunchKernelGGL(scan3_kernel, dim3(1024), dim3(256), 0, stream, rowptr, bsum, fill, n, E);
    hipLaunchKernelGGL(scatter_kernel, dim3(2048), dim3(256), 0, stream, EI, E, flag, fill, csr, n);

    // layer 1 transform: G = f16((X@W1)*dinv)
    hipLaunchKernelGGL((gemm_kernel<K1, 8>), dim3(2048), dim3(256), 0, stream, X, W1, dinv, G, n);
    // fused: gather(G) -> relu -> @W2 -> G2
    hipLaunchKernelGGL(gather_fused_kernel, dim3(2048), dim3(256), 0, stream,
                       rowptr, csr, G, dinv, b1, W2, G2, n);
    // final gather + bias + log_softmax
    const int ngb = (n + 3) / 4;
    hipLaunchKernelGGL(gather_ls_kernel, dim3(ngb), dim3(256), 0, stream,
                       rowptr, csr, G2, dinv, b2, Out, n);
}